// Round 14
// baseline (79.606 us; speedup 1.0000x reference)
//
#include <hip/hip_runtime.h>
#include <stdint.h>

#define T_STEPS 2048
#define LAST (T_STEPS - 1)
#define NSTEP (T_STEPS - 1)      // 2047 leapfrog steps total

struct F3 { float x, y, z; };

__device__ __forceinline__ F3 fma3(float a, F3 b, F3 c) {
    return { fmaf(a, b.x, c.x), fmaf(a, b.y, c.y), fmaf(a, b.z, c.z) };
}

__device__ __forceinline__ uint32_t rotl32(uint32_t v, int r) {
    return (v << r) | (v >> (32 - r));
}

// JAX Threefry-2x32, 20 rounds.
__device__ __forceinline__ void tf2x32(uint32_t k0, uint32_t k1, uint32_t c0, uint32_t c1,
                                       uint32_t &o0, uint32_t &o1) {
    uint32_t ks2 = k0 ^ k1 ^ 0x1BD11BDAu;
    uint32_t x0 = c0 + k0, x1 = c1 + k1;
#define TF_R(r) { x0 += x1; x1 = rotl32(x1, r); x1 ^= x0; }
    TF_R(13) TF_R(15) TF_R(26) TF_R(6)   x0 += k1;  x1 += ks2 + 1u;
    TF_R(17) TF_R(29) TF_R(16) TF_R(24)  x0 += ks2; x1 += k0 + 2u;
    TF_R(13) TF_R(15) TF_R(26) TF_R(6)   x0 += k0;  x1 += k1 + 3u;
    TF_R(17) TF_R(29) TF_R(16) TF_R(24)  x0 += k1;  x1 += ks2 + 4u;
    TF_R(13) TF_R(15) TF_R(26) TF_R(6)   x0 += ks2; x1 += k0 + 5u;
#undef TF_R
    o0 = x0; o1 = x1;
}

// XLA ErfInv32 (Giles), w = -log1p(-x*x)
__device__ __forceinline__ float erfinv32(float x) {
    float w = -log1pf(-x * x);
    float p;
    if (w < 5.0f) {
        w -= 2.5f;
        p =              2.81022636e-08f;
        p = fmaf(p, w,   3.43273939e-07f);
        p = fmaf(p, w,  -3.5233877e-06f);
        p = fmaf(p, w,  -4.39150654e-06f);
        p = fmaf(p, w,   0.00021858087f);
        p = fmaf(p, w,  -0.00125372503f);
        p = fmaf(p, w,  -0.00417768164f);
        p = fmaf(p, w,   0.246640727f);
        p = fmaf(p, w,   1.50140941f);
    } else {
        w = sqrtf(w) - 3.0f;
        p =             -0.000200214257f;
        p = fmaf(p, w,   0.000100950558f);
        p = fmaf(p, w,   0.00134934322f);
        p = fmaf(p, w,  -0.00367342844f);
        p = fmaf(p, w,   0.00573950773f);
        p = fmaf(p, w,  -0.0076224613f);
        p = fmaf(p, w,   0.00943887047f);
        p = fmaf(p, w,   1.00167406f);
        p = fmaf(p, w,   2.83297682f);
    }
    return p * x;
}

// jax.random.normal (threefry, partitionable path): bits = x0^x1 of E(key,(0,idx))
__device__ __forceinline__ float jax_normal(uint32_t ka, uint32_t kb, uint32_t idx) {
    uint32_t o0, o1;
    tf2x32(ka, kb, 0u, idx, o0, o1);
    uint32_t bits = o0 ^ o1;
    float f = __uint_as_float((bits >> 9) | 0x3F800000u) - 1.0f;  // [0,1)
    const float LO = -0.99999994f;                                 // nextafter(-1,0)
    float u = fmaxf(LO, fmaf(f, 2.0f, LO));                        // hi-lo rounds to 2.0f
    return 1.41421356f * erfinv32(u);
}

#define SB() __builtin_amdgcn_sched_barrier(0)

// R12 arithmetic (d-form + 1-Newton iv carry), distance->=2 round-robin order.
// IVP = predicted iv for this step (= ivpr of prev step); ICL = corrected iv of
// prev step; outputs ICO (corrected iv this step), IPO (prediction for next).
// Every consumer >=2 instrs after its producer, incl. across macro boundaries.
#define STEP_RR(IVP, ICL, ICO, IPO) { \
    float r2a_ = fmaf(xx, xx, b2);            SB(); \
    float t2_  = (IVP) * (IVP);               SB(); \
    float r2b_ = fmaf(xy, xy, r2a_);          SB(); \
    float nh_  = -0.5f * t2_;                 SB(); \
    float r2c_ = fmaf(xz, xz, r2b_);          SB(); \
    float tw_  = t2_ * (IVP);                 SB(); \
    float f0_  = fmaf(nh_, r2c_, 1.5f);       SB(); \
    float co_  = coef_s * tw_;                SB(); \
    float f02_ = f0_ * f0_;                   SB(); \
    float cf_  = co_ * f0_;                   SB(); \
    ICO = (IVP) * f0_;                        SB(); \
    float cf3_ = cf_ * f02_;                  SB(); \
    IPO = fmaf(2.0f, ICO, -(ICL));            SB(); \
    dx = fmaf(cf3_, xx, dx);                  SB(); \
    dy = fmaf(cf3_, xy, dy);                  SB(); \
    dz = fmaf(cf3_, xz, dz);                  SB(); \
    xx = xx + dx;                             SB(); \
    xy = xy + dy;                             SB(); \
    xz = xz + dz;                             SB(); \
}

// integrate `rem` uniform-dt steps: exact v_rsq half-kick entry/exit;
// nm = rem-1 interior iterations, 8x unrolled with A/B carry banks (no copies).
#define RUN_PHASE(rem) \
    if ((rem) > 0) { \
        float r2e = fmaf(x.z, x.z, fmaf(x.y, x.y, fmaf(x.x, x.x, b2))); \
        float iv; \
        asm("v_rsq_f32 %0, %1" : "=v"(iv) : "v"(r2e)); \
        float iv2e = iv * iv; \
        float ce   = (gmneg * iv) * iv2e; \
        F3 a0 = { ce * x.x, ce * x.y, ce * x.z }; \
        v = fma3(hdt, a0, v);                      /* entry half kick (exact) */ \
        float xx = x.x, xy = x.y, xz = x.z; \
        float dx = dt * v.x, dy = dt * v.y, dz = dt * v.z; \
        xx += dx; xy += dy; xz += dz;              /* first drift */ \
        float pA = iv, cA = iv;                    /* IVP, ICL banks */ \
        float pB, cB; \
        const int nm = (rem) - 1; \
        int i = 0; \
        while (i + 8 <= nm) { \
            STEP_RR(pA, cA, cB, pB) \
            STEP_RR(pB, cB, cA, pA) \
            STEP_RR(pA, cA, cB, pB) \
            STEP_RR(pB, cB, cA, pA) \
            STEP_RR(pA, cA, cB, pB) \
            STEP_RR(pB, cB, cA, pA) \
            STEP_RR(pA, cA, cB, pB) \
            STEP_RR(pB, cB, cA, pA) \
            i += 8; \
        } \
        while (i < nm) { \
            STEP_RR(pA, cA, cB, pB) \
            pA = pB; cA = cB; \
            ++i; \
        } \
        float r2x = fmaf(xz, xz, fmaf(xy, xy, fmaf(xx, xx, b2))); \
        float ivE; \
        asm("v_rsq_f32 %0, %1" : "=v"(ivE) : "v"(r2x)); \
        float cx = (gmneg * ivE) * (ivE * ivE); \
        x.x = xx; x.y = xy; x.z = xz; \
        v.x = fmaf(hdt, cx * x.x, dx * rdt);       /* v = d/dt + h*a (exact) */ \
        v.y = fmaf(hdt, cx * x.y, dy * rdt); \
        v.z = fmaf(hdt, cx * x.z, dz * rdt); \
    }

// thread layout: gid = 2*t + role; role 0 = lead, 1 = trail
__global__ void __launch_bounds__(64)
fused_kernel(const float* __restrict__ ts,
             const float* __restrict__ w0,
             const float* __restrict__ mass_p,
             const float* __restrict__ gm_p,
             const float* __restrict__ b_p,
             const int*   __restrict__ seed_p,
             float* __restrict__ w_lead,
             float* __restrict__ w_trail,
             float* __restrict__ prog) {
    const int gid  = blockIdx.x * blockDim.x + threadIdx.x;
    const int t    = gid >> 1;
    const int role = gid & 1;           // 0 = lead, 1 = trail
    if (t >= T_STEPS) return;

    const float gm = gm_p[0];
    const float gmneg = -gm;
    const float bb = b_p[0];
    const float b2 = bb * bb;
    const float pm = mass_p[0];
    const uint32_t seed = (uint32_t)seed_p[0];

    // uniform time step (linspace grid): scalar constants
    const float ts0 = ts[0];
    const float tsL = ts[LAST];
    const float dt  = (tsL - ts0) / (float)NSTEP;
    const float hdt = 0.5f * dt;
    const float rdt = 1.0f / dt;
    const float coef_s = (gmneg * dt) * dt;

    // ---------- Phase A: progenitor, steps [0, t) ----------
    F3 x = { w0[0], w0[1], w0[2] };
    F3 v = { w0[3], w0[4], w0[5] };

    RUN_PHASE(t)
    // (x, v) = prog full state at index t

    if (role == 0) {
        float* row = prog + 6 * t;
        row[0] = x.x; row[1] = x.y; row[2] = x.z;
        row[3] = v.x; row[4] = v.y; row[5] = v.z;
    }

    // ---------- initial conditions: scatter + RNG ----------
    uint32_t kpa, kpb, kva, kvb;
    tf2x32(0u, seed, 0u, (uint32_t)role,       kpa, kpb);
    tf2x32(0u, seed, 0u, (uint32_t)(2 + role), kva, kvb);

    float r   = sqrtf(fmaf(x.z, x.z, fmaf(x.y, x.y, x.x * x.x)));
    float cb  = powf(pm / (3.0f * gm), 1.0f / 3.0f);
    float rt  = r * cb;
    float sig = sqrtf(pm / (rt + 1e-8f));
    F3 rhat = { x.x / r, x.y / r, x.z / r };

    uint32_t base3 = 3u * (uint32_t)t;
    F3 np = { jax_normal(kpa, kpb, base3 + 0u), jax_normal(kpa, kpb, base3 + 1u), jax_normal(kpa, kpb, base3 + 2u) };
    F3 nv = { jax_normal(kva, kvb, base3 + 0u), jax_normal(kva, kvb, base3 + 1u), jax_normal(kva, kvb, base3 + 2u) };

    float ps  = 0.25f * rt;
    float vsc = 0.3f  * sig;
    float sgn = role ? 1.0f : -1.0f;
    F3 off = { sgn * (rt * rhat.x), sgn * (rt * rhat.y), sgn * (rt * rhat.z) };

    x = F3{ (x.x + off.x) + ps * np.x, (x.y + off.y) + ps * np.y, (x.z + off.z) + ps * np.z };
    v = F3{ v.x + vsc * nv.x, v.y + vsc * nv.y, v.z + vsc * nv.z };

    // ---------- Phase B: stream, steps [t, 2047) ----------
    RUN_PHASE(LAST - t)

    float* o = (role ? w_trail : w_lead) + 6 * t;
    o[0] = x.x; o[1] = x.y; o[2] = x.z;
    o[3] = v.x; o[4] = v.y; o[5] = v.z;
}

extern "C" void kernel_launch(void* const* d_in, const int* in_sizes, int n_in,
                              void* d_out, int out_size, void* d_ws, size_t ws_size,
                              hipStream_t stream) {
    const float* ts   = (const float*)d_in[0];
    const float* w0   = (const float*)d_in[1];
    const float* pm   = (const float*)d_in[2];
    const float* gm   = (const float*)d_in[3];
    const float* b    = (const float*)d_in[4];
    const int*   seed = (const int*)d_in[5];

    float* out     = (float*)d_out;
    float* w_lead  = out;
    float* w_trail = out + (size_t)T_STEPS * 6;
    float* prog    = out + (size_t)T_STEPS * 12;

    hipLaunchKernelGGL(fused_kernel, dim3(2 * T_STEPS / 64), dim3(64), 0, stream,
                       ts, w0, pm, gm, b, seed, w_lead, w_trail, prog);
}

// Round 15
// 72.784 us; speedup vs baseline: 1.0937x; 1.0937x over previous
//
#include <hip/hip_runtime.h>
#include <stdint.h>

#define T_STEPS 2048
#define LAST (T_STEPS - 1)
#define NSTEP (T_STEPS - 1)      // 2047 leapfrog steps total

struct F3 { float x, y, z; };

__device__ __forceinline__ F3 fma3(float a, F3 b, F3 c) {
    return { fmaf(a, b.x, c.x), fmaf(a, b.y, c.y), fmaf(a, b.z, c.z) };
}

__device__ __forceinline__ uint32_t rotl32(uint32_t v, int r) {
    return (v << r) | (v >> (32 - r));
}

// JAX Threefry-2x32, 20 rounds.
__device__ __forceinline__ void tf2x32(uint32_t k0, uint32_t k1, uint32_t c0, uint32_t c1,
                                       uint32_t &o0, uint32_t &o1) {
    uint32_t ks2 = k0 ^ k1 ^ 0x1BD11BDAu;
    uint32_t x0 = c0 + k0, x1 = c1 + k1;
#define TF_R(r) { x0 += x1; x1 = rotl32(x1, r); x1 ^= x0; }
    TF_R(13) TF_R(15) TF_R(26) TF_R(6)   x0 += k1;  x1 += ks2 + 1u;
    TF_R(17) TF_R(29) TF_R(16) TF_R(24)  x0 += ks2; x1 += k0 + 2u;
    TF_R(13) TF_R(15) TF_R(26) TF_R(6)   x0 += k0;  x1 += k1 + 3u;
    TF_R(17) TF_R(29) TF_R(16) TF_R(24)  x0 += k1;  x1 += ks2 + 4u;
    TF_R(13) TF_R(15) TF_R(26) TF_R(6)   x0 += ks2; x1 += k0 + 5u;
#undef TF_R
    o0 = x0; o1 = x1;
}

// XLA ErfInv32 (Giles), w = -log1p(-x*x)
__device__ __forceinline__ float erfinv32(float x) {
    float w = -log1pf(-x * x);
    float p;
    if (w < 5.0f) {
        w -= 2.5f;
        p =              2.81022636e-08f;
        p = fmaf(p, w,   3.43273939e-07f);
        p = fmaf(p, w,  -3.5233877e-06f);
        p = fmaf(p, w,  -4.39150654e-06f);
        p = fmaf(p, w,   0.00021858087f);
        p = fmaf(p, w,  -0.00125372503f);
        p = fmaf(p, w,  -0.00417768164f);
        p = fmaf(p, w,   0.246640727f);
        p = fmaf(p, w,   1.50140941f);
    } else {
        w = sqrtf(w) - 3.0f;
        p =             -0.000200214257f;
        p = fmaf(p, w,   0.000100950558f);
        p = fmaf(p, w,   0.00134934322f);
        p = fmaf(p, w,  -0.00367342844f);
        p = fmaf(p, w,   0.00573950773f);
        p = fmaf(p, w,  -0.0076224613f);
        p = fmaf(p, w,   0.00943887047f);
        p = fmaf(p, w,   1.00167406f);
        p = fmaf(p, w,   2.83297682f);
    }
    return p * x;
}

// jax.random.normal (threefry, partitionable path): bits = x0^x1 of E(key,(0,idx))
__device__ __forceinline__ float jax_normal(uint32_t ka, uint32_t kb, uint32_t idx) {
    uint32_t o0, o1;
    tf2x32(ka, kb, 0u, idx, o0, o1);
    uint32_t bits = o0 ^ o1;
    float f = __uint_as_float((bits >> 9) | 0x3F800000u) - 1.0f;  // [0,1)
    const float LO = -0.99999994f;                                 // nextafter(-1,0)
    float u = fmaxf(LO, fmaf(f, 2.0f, LO));                        // hi-lo rounds to 2.0f
    return 1.41421356f * erfinv32(u);
}

// 17-inst interior step (d-form, e3-folded cubic, Newton-anchored iv carry).
//   carried: nh3 = -1.5*ic^2, co = cs*ic^3, ic (corrected rsqrt), icd3 = ic/3.
//   e3 = fma(nh3, r2, 1.5) = 3*(Newton residual);  cf3 = co*(1+e3) ~ cs*r2^-1.5
//   d += cf3*x; x += d;  then re-anchor: ic = fma(icd3, e3, ic) (1-Newton), and
//   rebuild icd3/t2/nh3/tw/co from ic. f0^3 vs 1+e3: diff O(e^2) < f32 ulp.
#define STEP_E { \
    float r2a = fmaf(xx, xx, b2); \
    float r2b = fmaf(xy, xy, r2a); \
    float r2c = fmaf(xz, xz, r2b); \
    float e3  = fmaf(nh3, r2c, 1.5f); \
    float cf3 = fmaf(co, e3, co); \
    dx = fmaf(cf3, xx, dx); \
    dy = fmaf(cf3, xy, dy); \
    dz = fmaf(cf3, xz, dz); \
    xx += dx; xy += dy; xz += dz; \
    ic   = fmaf(icd3, e3, ic); \
    icd3 = 0.33333334f * ic; \
    float t2 = ic * ic; \
    nh3 = -1.5f * t2; \
    float tw = t2 * ic; \
    co  = coef_s * tw; \
}

// integrate `rem` uniform-dt steps: exact v_rsq half-kick entry/exit;
// nm = rem-1 interior iterations. No LDS, no per-step loads, no reg banks.
#define RUN_PHASE(rem) \
    if ((rem) > 0) { \
        float r2e = fmaf(x.z, x.z, fmaf(x.y, x.y, fmaf(x.x, x.x, b2))); \
        float iv; \
        asm("v_rsq_f32 %0, %1" : "=v"(iv) : "v"(r2e)); \
        float iv2e = iv * iv; \
        float ce   = (gmneg * iv) * iv2e; \
        F3 a0 = { ce * x.x, ce * x.y, ce * x.z }; \
        v = fma3(hdt, a0, v);                      /* entry half kick (exact) */ \
        float xx = x.x, xy = x.y, xz = x.z; \
        float dx = dt * v.x, dy = dt * v.y, dz = dt * v.z; \
        xx += dx; xy += dy; xz += dz;              /* first drift */ \
        float ic   = iv; \
        float icd3 = 0.33333334f * iv; \
        float nh3  = -1.5f * iv2e; \
        float co   = coef_s * (iv2e * iv); \
        const int nm = (rem) - 1; \
        int i = 0; \
        while (i + 8 <= nm) { \
            STEP_E STEP_E STEP_E STEP_E STEP_E STEP_E STEP_E STEP_E \
            i += 8; \
        } \
        while (i < nm) { STEP_E ++i; } \
        float r2x = fmaf(xz, xz, fmaf(xy, xy, fmaf(xx, xx, b2))); \
        float ivE; \
        asm("v_rsq_f32 %0, %1" : "=v"(ivE) : "v"(r2x)); \
        float cx = (gmneg * ivE) * (ivE * ivE); \
        x.x = xx; x.y = xy; x.z = xz; \
        v.x = fmaf(hdt, cx * x.x, dx * rdt);       /* v = d/dt + h*a (exact) */ \
        v.y = fmaf(hdt, cx * x.y, dy * rdt); \
        v.z = fmaf(hdt, cx * x.z, dz * rdt); \
    }

// thread layout: gid = 2*t + role; role 0 = lead, 1 = trail
__global__ void __launch_bounds__(64)
fused_kernel(const float* __restrict__ ts,
             const float* __restrict__ w0,
             const float* __restrict__ mass_p,
             const float* __restrict__ gm_p,
             const float* __restrict__ b_p,
             const int*   __restrict__ seed_p,
             float* __restrict__ w_lead,
             float* __restrict__ w_trail,
             float* __restrict__ prog) {
    const int gid  = blockIdx.x * blockDim.x + threadIdx.x;
    const int t    = gid >> 1;
    const int role = gid & 1;           // 0 = lead, 1 = trail
    if (t >= T_STEPS) return;

    const float gm = gm_p[0];
    const float gmneg = -gm;
    const float bb = b_p[0];
    const float b2 = bb * bb;
    const float pm = mass_p[0];
    const uint32_t seed = (uint32_t)seed_p[0];

    // uniform time step (linspace grid): scalar constants
    const float ts0 = ts[0];
    const float tsL = ts[LAST];
    const float dt  = (tsL - ts0) / (float)NSTEP;
    const float hdt = 0.5f * dt;
    const float rdt = 1.0f / dt;
    const float coef_s = (gmneg * dt) * dt;

    // ---------- Phase A: progenitor, steps [0, t) ----------
    F3 x = { w0[0], w0[1], w0[2] };
    F3 v = { w0[3], w0[4], w0[5] };

    RUN_PHASE(t)
    // (x, v) = prog full state at index t

    if (role == 0) {
        float* row = prog + 6 * t;
        row[0] = x.x; row[1] = x.y; row[2] = x.z;
        row[3] = v.x; row[4] = v.y; row[5] = v.z;
    }

    // ---------- initial conditions: scatter + RNG ----------
    uint32_t kpa, kpb, kva, kvb;
    tf2x32(0u, seed, 0u, (uint32_t)role,       kpa, kpb);
    tf2x32(0u, seed, 0u, (uint32_t)(2 + role), kva, kvb);

    float r   = sqrtf(fmaf(x.z, x.z, fmaf(x.y, x.y, x.x * x.x)));
    float cb  = powf(pm / (3.0f * gm), 1.0f / 3.0f);
    float rt  = r * cb;
    float sig = sqrtf(pm / (rt + 1e-8f));
    F3 rhat = { x.x / r, x.y / r, x.z / r };

    uint32_t base3 = 3u * (uint32_t)t;
    F3 np = { jax_normal(kpa, kpb, base3 + 0u), jax_normal(kpa, kpb, base3 + 1u), jax_normal(kpa, kpb, base3 + 2u) };
    F3 nv = { jax_normal(kva, kvb, base3 + 0u), jax_normal(kva, kvb, base3 + 1u), jax_normal(kva, kvb, base3 + 2u) };

    float ps  = 0.25f * rt;
    float vsc = 0.3f  * sig;
    float sgn = role ? 1.0f : -1.0f;
    F3 off = { sgn * (rt * rhat.x), sgn * (rt * rhat.y), sgn * (rt * rhat.z) };

    x = F3{ (x.x + off.x) + ps * np.x, (x.y + off.y) + ps * np.y, (x.z + off.z) + ps * np.z };
    v = F3{ v.x + vsc * nv.x, v.y + vsc * nv.y, v.z + vsc * nv.z };

    // ---------- Phase B: stream, steps [t, 2047) ----------
    RUN_PHASE(LAST - t)

    float* o = (role ? w_trail : w_lead) + 6 * t;
    o[0] = x.x; o[1] = x.y; o[2] = x.z;
    o[3] = v.x; o[4] = v.y; o[5] = v.z;
}

extern "C" void kernel_launch(void* const* d_in, const int* in_sizes, int n_in,
                              void* d_out, int out_size, void* d_ws, size_t ws_size,
                              hipStream_t stream) {
    const float* ts   = (const float*)d_in[0];
    const float* w0   = (const float*)d_in[1];
    const float* pm   = (const float*)d_in[2];
    const float* gm   = (const float*)d_in[3];
    const float* b    = (const float*)d_in[4];
    const int*   seed = (const int*)d_in[5];

    float* out     = (float*)d_out;
    float* w_lead  = out;
    float* w_trail = out + (size_t)T_STEPS * 6;
    float* prog    = out + (size_t)T_STEPS * 12;

    hipLaunchKernelGGL(fused_kernel, dim3(2 * T_STEPS / 64), dim3(64), 0, stream,
                       ts, w0, pm, gm, b, seed, w_lead, w_trail, prog);
}

// Round 16
// 55.282 us; speedup vs baseline: 1.4400x; 1.3166x over previous
//
#include <hip/hip_runtime.h>
#include <stdint.h>

#define T_STEPS 2048
#define LAST (T_STEPS - 1)
#define NSTEP (T_STEPS - 1)      // 2047 leapfrog steps total

struct F3 { float x, y, z; };

__device__ __forceinline__ F3 fma3(float a, F3 b, F3 c) {
    return { fmaf(a, b.x, c.x), fmaf(a, b.y, c.y), fmaf(a, b.z, c.z) };
}

__device__ __forceinline__ uint32_t rotl32(uint32_t v, int r) {
    return (v << r) | (v >> (32 - r));
}

// JAX Threefry-2x32, 20 rounds.
__device__ __forceinline__ void tf2x32(uint32_t k0, uint32_t k1, uint32_t c0, uint32_t c1,
                                       uint32_t &o0, uint32_t &o1) {
    uint32_t ks2 = k0 ^ k1 ^ 0x1BD11BDAu;
    uint32_t x0 = c0 + k0, x1 = c1 + k1;
#define TF_R(r) { x0 += x1; x1 = rotl32(x1, r); x1 ^= x0; }
    TF_R(13) TF_R(15) TF_R(26) TF_R(6)   x0 += k1;  x1 += ks2 + 1u;
    TF_R(17) TF_R(29) TF_R(16) TF_R(24)  x0 += ks2; x1 += k0 + 2u;
    TF_R(13) TF_R(15) TF_R(26) TF_R(6)   x0 += k0;  x1 += k1 + 3u;
    TF_R(17) TF_R(29) TF_R(16) TF_R(24)  x0 += k1;  x1 += ks2 + 4u;
    TF_R(13) TF_R(15) TF_R(26) TF_R(6)   x0 += ks2; x1 += k0 + 5u;
#undef TF_R
    o0 = x0; o1 = x1;
}

// XLA ErfInv32 (Giles), w = -log1p(-x*x)
__device__ __forceinline__ float erfinv32(float x) {
    float w = -log1pf(-x * x);
    float p;
    if (w < 5.0f) {
        w -= 2.5f;
        p =              2.81022636e-08f;
        p = fmaf(p, w,   3.43273939e-07f);
        p = fmaf(p, w,  -3.5233877e-06f);
        p = fmaf(p, w,  -4.39150654e-06f);
        p = fmaf(p, w,   0.00021858087f);
        p = fmaf(p, w,  -0.00125372503f);
        p = fmaf(p, w,  -0.00417768164f);
        p = fmaf(p, w,   0.246640727f);
        p = fmaf(p, w,   1.50140941f);
    } else {
        w = sqrtf(w) - 3.0f;
        p =             -0.000200214257f;
        p = fmaf(p, w,   0.000100950558f);
        p = fmaf(p, w,   0.00134934322f);
        p = fmaf(p, w,  -0.00367342844f);
        p = fmaf(p, w,   0.00573950773f);
        p = fmaf(p, w,  -0.0076224613f);
        p = fmaf(p, w,   0.00943887047f);
        p = fmaf(p, w,   1.00167406f);
        p = fmaf(p, w,   2.83297682f);
    }
    return p * x;
}

// jax.random.normal (threefry, partitionable path): bits = x0^x1 of E(key,(0,idx))
__device__ __forceinline__ float jax_normal(uint32_t ka, uint32_t kb, uint32_t idx) {
    uint32_t o0, o1;
    tf2x32(ka, kb, 0u, idx, o0, o1);
    uint32_t bits = o0 ^ o1;
    float f = __uint_as_float((bits >> 9) | 0x3F800000u) - 1.0f;  // [0,1)
    const float LO = -0.99999994f;                                 // nextafter(-1,0)
    float u = fmaxf(LO, fmaf(f, 2.0f, LO));                        // hi-lo rounds to 2.0f
    return 1.41421356f * erfinv32(u);
}

// 12-inst interior step: Stormer-Verlet position form + Newton-carried rsqrt.
//   carriers: ic ~ r2^{-1/2} (Newton-corrected each step), nh1 = -0.5*ic^2.
//   e  = fma(nh1, r2, 1.5)  (Newton factor; =1+O(dr2^2))
//   ic = ic*e               (1-Newton correction against CURRENT r2)
//   c2 = fma(cs, ic^3, 2.0) (cs = -gm*dt^2; c2 = 2 + dt^2*accel_coef)
//   x' = c2*x - xp          (leapfrog second-difference form; xp<-x rename)
#define STEP_X { \
    float r2a = fmaf(xx, xx, b2); \
    float r2b = fmaf(xy, xy, r2a); \
    float r2c = fmaf(xz, xz, r2b); \
    float e_  = fmaf(nh1, r2c, 1.5f); \
    ic = ic * e_; \
    float t2 = ic * ic; \
    nh1 = -0.5f * t2; \
    float tw = t2 * ic; \
    float c2 = fmaf(coef_s, tw, 2.0f); \
    float xn_ = fmaf(c2, xx, -xpx); xpx = xx; xx = xn_; \
    float yn_ = fmaf(c2, xy, -xpy); xpy = xy; xy = yn_; \
    float zn_ = fmaf(c2, xz, -xpz); xpz = xz; xz = zn_; \
}

// integrate `rem` uniform-dt steps: exact v_rsq half-kick entry/exit;
// nm = rem-1 interior iterations. No LDS, no per-step loads.
#define RUN_PHASE(rem) \
    if ((rem) > 0) { \
        float r2e = fmaf(x.z, x.z, fmaf(x.y, x.y, fmaf(x.x, x.x, b2))); \
        float iv; \
        asm("v_rsq_f32 %0, %1" : "=v"(iv) : "v"(r2e)); \
        float iv2e = iv * iv; \
        float ce   = (gmneg * iv) * iv2e; \
        F3 a0 = { ce * x.x, ce * x.y, ce * x.z }; \
        v = fma3(hdt, a0, v);                      /* entry half kick (exact) */ \
        float xx = x.x, xy = x.y, xz = x.z; \
        float dx0 = dt * v.x, dy0 = dt * v.y, dz0 = dt * v.z; \
        xx += dx0; xy += dy0; xz += dz0;           /* first drift */ \
        float xpx = xx - dx0, xpy = xy - dy0, xpz = xz - dz0;  /* x_{n-1} */ \
        float ic  = iv; \
        float nh1 = -0.5f * iv2e; \
        const int nm = (rem) - 1; \
        int i = 0; \
        while (i + 8 <= nm) { \
            STEP_X STEP_X STEP_X STEP_X STEP_X STEP_X STEP_X STEP_X \
            i += 8; \
        } \
        while (i < nm) { STEP_X ++i; } \
        float ddx = xx - xpx, ddy = xy - xpy, ddz = xz - xpz;  /* = dt*v_half */ \
        float r2x = fmaf(xz, xz, fmaf(xy, xy, fmaf(xx, xx, b2))); \
        float ivE; \
        asm("v_rsq_f32 %0, %1" : "=v"(ivE) : "v"(r2x)); \
        float cx = (gmneg * ivE) * (ivE * ivE); \
        x.x = xx; x.y = xy; x.z = xz; \
        v.x = fmaf(hdt, cx * x.x, ddx * rdt);      /* v = d/dt + h*a (exact) */ \
        v.y = fmaf(hdt, cx * x.y, ddy * rdt); \
        v.z = fmaf(hdt, cx * x.z, ddz * rdt); \
    }

// thread layout: gid = 2*t + role; role 0 = lead, 1 = trail
__global__ void __launch_bounds__(64)
fused_kernel(const float* __restrict__ ts,
             const float* __restrict__ w0,
             const float* __restrict__ mass_p,
             const float* __restrict__ gm_p,
             const float* __restrict__ b_p,
             const int*   __restrict__ seed_p,
             float* __restrict__ w_lead,
             float* __restrict__ w_trail,
             float* __restrict__ prog) {
    const int gid  = blockIdx.x * blockDim.x + threadIdx.x;
    const int t    = gid >> 1;
    const int role = gid & 1;           // 0 = lead, 1 = trail
    if (t >= T_STEPS) return;

    const float gm = gm_p[0];
    const float gmneg = -gm;
    const float bb = b_p[0];
    const float b2 = bb * bb;
    const float pm = mass_p[0];
    const uint32_t seed = (uint32_t)seed_p[0];

    // uniform time step (linspace grid): scalar constants
    const float ts0 = ts[0];
    const float tsL = ts[LAST];
    const float dt  = (tsL - ts0) / (float)NSTEP;
    const float hdt = 0.5f * dt;
    const float rdt = 1.0f / dt;
    const float coef_s = (gmneg * dt) * dt;

    // ---------- Phase A: progenitor, steps [0, t) ----------
    F3 x = { w0[0], w0[1], w0[2] };
    F3 v = { w0[3], w0[4], w0[5] };

    RUN_PHASE(t)
    // (x, v) = prog full state at index t

    if (role == 0) {
        float* row = prog + 6 * t;
        row[0] = x.x; row[1] = x.y; row[2] = x.z;
        row[3] = v.x; row[4] = v.y; row[5] = v.z;
    }

    // ---------- initial conditions: scatter + RNG ----------
    uint32_t kpa, kpb, kva, kvb;
    tf2x32(0u, seed, 0u, (uint32_t)role,       kpa, kpb);
    tf2x32(0u, seed, 0u, (uint32_t)(2 + role), kva, kvb);

    float r   = sqrtf(fmaf(x.z, x.z, fmaf(x.y, x.y, x.x * x.x)));
    float cb  = powf(pm / (3.0f * gm), 1.0f / 3.0f);
    float rt  = r * cb;
    float sig = sqrtf(pm / (rt + 1e-8f));
    F3 rhat = { x.x / r, x.y / r, x.z / r };

    uint32_t base3 = 3u * (uint32_t)t;
    F3 np = { jax_normal(kpa, kpb, base3 + 0u), jax_normal(kpa, kpb, base3 + 1u), jax_normal(kpa, kpb, base3 + 2u) };
    F3 nv = { jax_normal(kva, kvb, base3 + 0u), jax_normal(kva, kvb, base3 + 1u), jax_normal(kva, kvb, base3 + 2u) };

    float ps  = 0.25f * rt;
    float vsc = 0.3f  * sig;
    float sgn = role ? 1.0f : -1.0f;
    F3 off = { sgn * (rt * rhat.x), sgn * (rt * rhat.y), sgn * (rt * rhat.z) };

    x = F3{ (x.x + off.x) + ps * np.x, (x.y + off.y) + ps * np.y, (x.z + off.z) + ps * np.z };
    v = F3{ v.x + vsc * nv.x, v.y + vsc * nv.y, v.z + vsc * nv.z };

    // ---------- Phase B: stream, steps [t, 2047) ----------
    RUN_PHASE(LAST - t)

    float* o = (role ? w_trail : w_lead) + 6 * t;
    o[0] = x.x; o[1] = x.y; o[2] = x.z;
    o[3] = v.x; o[4] = v.y; o[5] = v.z;
}

extern "C" void kernel_launch(void* const* d_in, const int* in_sizes, int n_in,
                              void* d_out, int out_size, void* d_ws, size_t ws_size,
                              hipStream_t stream) {
    const float* ts   = (const float*)d_in[0];
    const float* w0   = (const float*)d_in[1];
    const float* pm   = (const float*)d_in[2];
    const float* gm   = (const float*)d_in[3];
    const float* b    = (const float*)d_in[4];
    const int*   seed = (const int*)d_in[5];

    float* out     = (float*)d_out;
    float* w_lead  = out;
    float* w_trail = out + (size_t)T_STEPS * 6;
    float* prog    = out + (size_t)T_STEPS * 12;

    hipLaunchKernelGGL(fused_kernel, dim3(2 * T_STEPS / 64), dim3(64), 0, stream,
                       ts, w0, pm, gm, b, seed, w_lead, w_trail, prog);
}